// Round 9
// baseline (318.840 us; speedup 1.0000x reference)
//
#include <hip/hip_runtime.h>

// Problem constants
#define B_     8
#define H_     512
#define W_     512
#define KK_    9
#define COUT_  3
#define HO_    510
#define WO_    510
#define PLANE_ (HO_ * WO_)      // 260100

// LDS window: 2 output rows per block, halo +-6 rows (+2 kernel), full width
// with an 8-col zero border on each side. Zero-padding semantics live in LDS.
#define XROWS_ 16               // rows XR0 .. XR0+15, XR0 = ho0-6
#define XCOLS_ 528              // cols -8 .. 519 (image cols 0..511 inside)
#define XSTR_  532              // row stride in dwords (mult of 4 -> 16B aligned rows)

typedef float f2 __attribute__((ext_vector_type(2)));

__device__ __forceinline__ int iclamp(int v, int lo, int hi) {
    return v < lo ? lo : (v > hi ? hi : v);
}

__global__ __launch_bounds__(512, 6) void dcn_fwd_kernel(
    const float* __restrict__ x,       // [B,1,512,512]
    const float* __restrict__ offset,  // [B,18,510,510]
    const float* __restrict__ mask,    // [B,9,510,510]
    const float* __restrict__ weight,  // [3,1,3,3]
    const float* __restrict__ bias,    // [3]
    float* __restrict__ out)           // [B,3,510,510]
{
    __shared__ float sx[XROWS_ * XSTR_];   // 34,048 B

    const int bid = blockIdx.x;            // 255 tiles * 8 batches = 2040
    const int b   = bid & 7;               // batch -> XCD (round-robin dispatch)
    const int q   = bid >> 3;              // row-tile 0..254
    const int ho0 = q * 2;
    const int XR0 = ho0 - 6;

    const int tid = threadIdx.x;
    const float* xb = x + b * (H_ * W_);

    // ---- stage zero-bordered x window (float4 chunks; border chunks are whole) ----
    // 16 rows * 132 float4-chunks; chunk wc4 covers window cols [4*wc4, 4*wc4+3],
    // image cols 4*wc4-8 .. ; wc4 in [2,129] <=> fully inside image columns.
    for (int i = tid; i < XROWS_ * 132; i += 512) {
        const int wr  = i / 132;
        const int wc4 = i - wr * 132;
        const int yr  = XR0 + wr;
        float4 v = make_float4(0.f, 0.f, 0.f, 0.f);
        if (((unsigned)yr < 512u) & (wc4 >= 2) & (wc4 <= 129)) {
            v = *(const float4*)(xb + yr * W_ + (wc4 * 4 - 8));
        }
        *(float4*)(&sx[wr * XSTR_ + wc4 * 4]) = v;
    }
    __syncthreads();

    // ---- output mapping: 2 px (f2) per thread, full-width rows ----
    const int r  = tid >> 8;               // 0..1
    const int j  = tid & 255;              // pair index
    int wo0 = 2 * j;
    if (wo0 > WO_ - 2) wo0 = WO_ - 2;      // j=255 duplicates pair 254 (benign)
    const int ho = ho0 + r;

    const int pix   = ho * WO_ + wo0;
    const int obase = b * (2 * KK_) * PLANE_ + pix;
    const int mbase = b * KK_ * PLANE_ + pix;

    // weights/bias: uniform -> scalar broadcast
    float w0[KK_], w1[KK_], w2[KK_];
    #pragma unroll
    for (int k = 0; k < KK_; ++k) {
        w0[k] = weight[0 * KK_ + k];
        w1[k] = weight[1 * KK_ + k];
        w2[k] = weight[2 * KK_ + k];
    }
    const float b0 = bias[0], b1 = bias[1], b2 = bias[2];

    const float fho = (float)ho;
    const float fwo = (float)wo0;

    float a00 = 0.f, a01 = 0.f;   // cout0 px{0,1}
    float a10 = 0.f, a11 = 0.f;
    float a20 = 0.f, a21 = 0.f;

    #pragma unroll
    for (int kh = 0; kh < 3; ++kh) {
        #pragma unroll
        for (int kw = 0; kw < 3; ++kw) {
            const int kk = kh * 3 + kw;
            const f2 dy2 = *(const f2*)(offset + obase + (2 * kk)     * PLANE_);
            const f2 dx2 = *(const f2*)(offset + obase + (2 * kk + 1) * PLANE_);
            const f2 m2  = *(const f2*)(mask   + mbase +  kk          * PLANE_);

            #pragma unroll
            for (int p = 0; p < 2; ++p) {
                const float py = (fho + (float)kh) + dy2[p];
                const float px = (fwo + (float)(kw + p)) + dx2[p];

                const float y0f = floorf(py);
                const float x0f = floorf(px);
                const float ly  = py - y0f;
                const float lx  = px - x0f;

                const int lr = (int)y0f - XR0;     // window row of top corner
                const int wc = (int)x0f + 8;       // window col of left corner

                float v00, v01, v10, v11;
                if (__builtin_expect(((unsigned)lr < 15u) & ((unsigned)wc < 527u), 1)) {
                    // window holds zero-padded image: no validity math needed
                    const int a = lr * XSTR_ + wc;
                    v00 = sx[a];
                    v01 = sx[a + 1];
                    v10 = sx[a + XSTR_];
                    v11 = sx[a + XSTR_ + 1];
                } else {
                    // |offset| > ~6: essentially never; full reference semantics
                    const float y1f = y0f + 1.0f, x1f = x0f + 1.0f;
                    const float vy0 = (y0f >= 0.f && y0f <= 511.f) ? 1.f : 0.f;
                    const float vy1 = (y1f >= 0.f && y1f <= 511.f) ? 1.f : 0.f;
                    const float vx0 = (x0f >= 0.f && x0f <= 511.f) ? 1.f : 0.f;
                    const float vx1 = (x1f >= 0.f && x1f <= 511.f) ? 1.f : 0.f;
                    const int yi0 = iclamp((int)y0f, 0, 511);
                    const int yi1 = iclamp((int)y1f, 0, 511);
                    const int xi0 = iclamp((int)x0f, 0, 511);
                    const int xi1 = iclamp((int)x1f, 0, 511);
                    v00 = xb[yi0 * W_ + xi0] * (vy0 * vx0);
                    v01 = xb[yi0 * W_ + xi1] * (vy0 * vx1);
                    v10 = xb[yi1 * W_ + xi0] * (vy1 * vx0);
                    v11 = xb[yi1 * W_ + xi1] * (vy1 * vx1);
                }

                const float top = fmaf(lx, v01 - v00, v00);
                const float bot = fmaf(lx, v11 - v10, v10);
                const float val = fmaf(ly, bot - top, top);
                const float s   = val * m2[p];
                if (p == 0) {
                    a00 = fmaf(w0[kk], s, a00);
                    a10 = fmaf(w1[kk], s, a10);
                    a20 = fmaf(w2[kk], s, a20);
                } else {
                    a01 = fmaf(w0[kk], s, a01);
                    a11 = fmaf(w1[kk], s, a11);
                    a21 = fmaf(w2[kk], s, a21);
                }
            }
        }
    }

    const int ob = b * COUT_ * PLANE_ + pix;
    f2 o0 = {a00 + b0, a01 + b0};
    f2 o1 = {a10 + b1, a11 + b1};
    f2 o2 = {a20 + b2, a21 + b2};
    *(f2*)(out + ob)              = o0;
    *(f2*)(out + ob + PLANE_)     = o1;
    *(f2*)(out + ob + 2 * PLANE_) = o2;
}

extern "C" void kernel_launch(void* const* d_in, const int* in_sizes, int n_in,
                              void* d_out, int out_size, void* d_ws, size_t ws_size,
                              hipStream_t stream) {
    const float* x      = (const float*)d_in[0];
    const float* offset = (const float*)d_in[1];
    const float* mask   = (const float*)d_in[2];
    const float* weight = (const float*)d_in[3];
    const float* bias   = (const float*)d_in[4];
    float* out = (float*)d_out;

    const int grid = (HO_ / 2) * B_;   // 255 row-tiles * 8 batches = 2040
    dcn_fwd_kernel<<<grid, 512, 0, stream>>>(x, offset, mask, weight, bias, out);
}

// Round 10
// 72.152 us; speedup vs baseline: 4.4190x; 4.4190x over previous
//
#include <hip/hip_runtime.h>

// Problem constants
#define B_    8
#define H_    512
#define W_    512
#define KK_   9
#define COUT_ 3
#define HO_   510
#define WO_   510
#define PLANE_ 260100           // HO_*WO_

typedef float f2 __attribute__((ext_vector_type(2)));

__device__ __forceinline__ int iclamp(int v, int lo, int hi) {
    return v < lo ? lo : (v > hi ? hi : v);
}

__global__ __launch_bounds__(256, 4) void dcn_fwd_kernel(
    const float* __restrict__ x,       // [B,1,512,512]
    const float* __restrict__ offset,  // [B,18,510,510]
    const float* __restrict__ mask,    // [B,9,510,510]
    const float* __restrict__ weight,  // [3,1,3,3]
    const float* __restrict__ bias,    // [3]
    float* __restrict__ out)           // [B,3,510,510]
{
    // one block = one output row (b, ho): both block-uniform -> SGPR bases
    const int bid = blockIdx.x;        // 0 .. 8*510-1
    const int ho  = bid % HO_;
    const int b   = bid / HO_;

    const int j   = threadIdx.x;       // 0..255, 2 px each
    int wo0 = 2 * j;
    if (wo0 > WO_ - 2) wo0 = WO_ - 2;  // j=255 duplicates last pair (benign)

    const int pix = ho * WO_ + wo0;
    const float* xb   = x + (b << 18);                 // b * 512*512
    const float* offb = offset + b * (2 * KK_ * PLANE_) + pix;
    const float* mb   = mask   + b * (KK_ * PLANE_)    + pix;

    // ---- phase 1: issue ALL 27 stream loads up front (explicit arrays) ----
    f2 dy2[KK_], dx2[KK_], m2[KK_];
    #pragma unroll
    for (int kk = 0; kk < KK_; ++kk) {
        dy2[kk] = *(const f2*)(offb + (2 * kk)     * PLANE_);
        dx2[kk] = *(const f2*)(offb + (2 * kk + 1) * PLANE_);
        m2[kk]  = *(const f2*)(mb   +  kk          * PLANE_);
    }

    // weights/bias: uniform addresses -> scalar broadcast loads
    float w0[KK_], w1[KK_], w2[KK_];
    #pragma unroll
    for (int k = 0; k < KK_; ++k) {
        w0[k] = weight[0 * KK_ + k];
        w1[k] = weight[1 * KK_ + k];
        w2[k] = weight[2 * KK_ + k];
    }
    const float b0 = bias[0], b1 = bias[1], b2 = bias[2];

    const float fho = (float)ho;
    const float fwo = (float)wo0;

    float a00 = 0.f, a01 = 0.f;
    float a10 = 0.f, a11 = 0.f;
    float a20 = 0.f, a21 = 0.f;

    // ---- phase 2: consume taps (gathers overlap across taps via unroll) ----
    #pragma unroll
    for (int kh = 0; kh < 3; ++kh) {
        #pragma unroll
        for (int kw = 0; kw < 3; ++kw) {
            const int kk = kh * 3 + kw;
            #pragma unroll
            for (int p = 0; p < 2; ++p) {
                const float py = (fho + (float)kh) + dy2[kk][p];
                const float px = (fwo + (float)(kw + p)) + dx2[kk][p];

                const float y0f = floorf(py);
                const float x0f = floorf(px);
                const float ly  = py - y0f;
                const float lx  = px - x0f;
                const float y1f = y0f + 1.0f;
                const float x1f = x0f + 1.0f;

                // validity on UNCLIPPED float corner coords (reference semantics)
                const float vy0 = (y0f >= 0.f && y0f <= 511.f) ? 1.f : 0.f;
                const float vy1 = (y1f >= 0.f && y1f <= 511.f) ? 1.f : 0.f;
                const float vx0 = (x0f >= 0.f && x0f <= 511.f) ? 1.f : 0.f;
                const float vx1 = (x1f >= 0.f && x1f <= 511.f) ? 1.f : 0.f;

                const int yi0 = iclamp((int)y0f, 0, 511);
                const int yi1 = iclamp((int)y1f, 0, 511);
                const int xi0 = iclamp((int)x0f, 0, 511);
                const int xi1 = iclamp((int)x1f, 0, 511);

                const float v00 = xb[(yi0 << 9) + xi0] * (vy0 * vx0);
                const float v01 = xb[(yi0 << 9) + xi1] * (vy0 * vx1);
                const float v10 = xb[(yi1 << 9) + xi0] * (vy1 * vx0);
                const float v11 = xb[(yi1 << 9) + xi1] * (vy1 * vx1);

                const float top = fmaf(lx, v01 - v00, v00);
                const float bot = fmaf(lx, v11 - v10, v10);
                const float val = fmaf(ly, bot - top, top);
                const float s   = val * m2[kk][p];

                if (p == 0) {
                    a00 = fmaf(w0[kk], s, a00);
                    a10 = fmaf(w1[kk], s, a10);
                    a20 = fmaf(w2[kk], s, a20);
                } else {
                    a01 = fmaf(w0[kk], s, a01);
                    a11 = fmaf(w1[kk], s, a11);
                    a21 = fmaf(w2[kk], s, a21);
                }
            }
        }
    }

    // ---- stores (f2, contiguous across the block's row) ----
    const int ob = b * (COUT_ * PLANE_) + pix;
    f2 o0 = {a00 + b0, a01 + b0};
    f2 o1 = {a10 + b1, a11 + b1};
    f2 o2 = {a20 + b2, a21 + b2};
    *(f2*)(out + ob)              = o0;
    *(f2*)(out + ob + PLANE_)     = o1;
    *(f2*)(out + ob + 2 * PLANE_) = o2;
}

extern "C" void kernel_launch(void* const* d_in, const int* in_sizes, int n_in,
                              void* d_out, int out_size, void* d_ws, size_t ws_size,
                              hipStream_t stream) {
    const float* x      = (const float*)d_in[0];
    const float* offset = (const float*)d_in[1];
    const float* mask   = (const float*)d_in[2];
    const float* weight = (const float*)d_in[3];
    const float* bias   = (const float*)d_in[4];
    float* out = (float*)d_out;

    const int grid = B_ * HO_;   // 4080 blocks, one output row each
    dcn_fwd_kernel<<<grid, 256, 0, stream>>>(x, offset, mask, weight, bias, out);
}